// Round 1
// 2687.713 us; speedup vs baseline: 1.1348x; 1.1348x over previous
//
#include <hip/hip_runtime.h>
#include <stdint.h>
#include <math.h>

#define T_TOKENS 8192
#define H_DIM    2048
#define I_DIM    16384
#define NEXP     5
#define RANK     16
#define LORA_SCALE 2.0f

typedef __attribute__((ext_vector_type(8))) short bf16x8;   // 8 bf16 in 4 VGPRs
typedef __attribute__((ext_vector_type(4))) float f32x4;

typedef const __attribute__((address_space(1))) void gv_t;  // global
typedef __attribute__((address_space(3))) void lv_t;        // LDS

__device__ __forceinline__ uint16_t f2bf(float f) {
  union { uint32_t u; float f; } v; v.f = f;
  uint32_t u = v.u;
  return (uint16_t)((u + 0x7fffu + ((u >> 16) & 1u)) >> 16);
}
__device__ __forceinline__ float bf2f(uint16_t b) {
  union { uint32_t u; float f; } v; v.u = ((uint32_t)b) << 16; return v.f;
}
__device__ __forceinline__ uint32_t pack2(float lo, float hi) {
  return (uint32_t)f2bf(lo) | ((uint32_t)f2bf(hi) << 16);
}
// gelu_tanh(x) == x * sigmoid(2*0.7978845608*(x + 0.044715 x^3)); __expf -> v_exp_f32
__device__ __forceinline__ float gelu_fast(float x) {
  float x3 = x * x * x;
  float z = 1.5957691216057308f * (x + 0.044715f * x3);
  return x / (1.0f + __expf(-z));
}

// ---------------------------------------------------------------------------
// Kernel 0: fp32 -> bf16 conversion (8 elements / thread)
// ---------------------------------------------------------------------------
__global__ __launch_bounds__(256) void cvt_kernel(
    const float* __restrict__ src, uint16_t* __restrict__ dst, int n8)
{
  int i = blockIdx.x * 256 + threadIdx.x;
  if (i >= n8) return;
  float4 a = ((const float4*)src)[2 * i];
  float4 b = ((const float4*)src)[2 * i + 1];
  uint4 o;
  o.x = pack2(a.x, a.y);
  o.y = pack2(a.z, a.w);
  o.z = pack2(b.x, b.y);
  o.w = pack2(b.z, b.w);
  ((uint4*)dst)[i] = o;
}

// ---------------------------------------------------------------------------
// Kernel 1: router logits -> softmax stats + rank-16 LoRA (fp32 in).
// Also emits the bf16 copy of X. One block (256 threads) per token.
// ---------------------------------------------------------------------------
__global__ __launch_bounds__(256) void router_lora_kernel(
    const float* __restrict__ X,     // [T, H] fp32
    const float* __restrict__ RW,    // [5, H]
    const float* __restrict__ LA,    // [4, 16, H]
    const float* __restrict__ LB,    // [4, H, 16]
    float* __restrict__ lora_out,    // [T, H] fp32  (== d_out)
    uint16_t* __restrict__ Xb,       // [T, H] bf16
    float* __restrict__ accum)       // [10] fp32 (probs sum, count sum)
{
  const int token = blockIdx.x;
  const int t = threadIdx.x;
  const int lane = t & 63, wid = t >> 6;

  __shared__ float red5[NEXP][4];
  __shared__ float logits_s[NEXP];
  __shared__ float tred[4][RANK];
  __shared__ float tvec[RANK];

  const float* x = X + (size_t)token * H_DIM;
  float4 xa = ((const float4*)x)[2 * t];
  float4 xb = ((const float4*)x)[2 * t + 1];
  float xv[8] = {xa.x, xa.y, xa.z, xa.w, xb.x, xb.y, xb.z, xb.w};

  // bf16 copy of X
  {
    uint4 o;
    o.x = pack2(xv[0], xv[1]);
    o.y = pack2(xv[2], xv[3]);
    o.z = pack2(xv[4], xv[5]);
    o.w = pack2(xv[6], xv[7]);
    ((uint4*)(Xb + (size_t)token * H_DIM))[t] = o;
  }

  // ---- logits ----
  float part[NEXP];
  #pragma unroll
  for (int e = 0; e < NEXP; e++) {
    const float* r = RW + e * H_DIM + t * 8;
    float4 ra = ((const float4*)r)[0];
    float4 rb = ((const float4*)r)[1];
    part[e] = xv[0]*ra.x + xv[1]*ra.y + xv[2]*ra.z + xv[3]*ra.w
            + xv[4]*rb.x + xv[5]*rb.y + xv[6]*rb.z + xv[7]*rb.w;
  }
  #pragma unroll
  for (int e = 0; e < NEXP; e++)
    #pragma unroll
    for (int off = 32; off > 0; off >>= 1)
      part[e] += __shfl_down(part[e], off, 64);
  if (lane == 0) {
    #pragma unroll
    for (int e = 0; e < NEXP; e++) red5[e][wid] = part[e];
  }
  __syncthreads();
  if (t == 0) {
    #pragma unroll
    for (int e = 0; e < NEXP; e++)
      logits_s[e] = red5[e][0] + red5[e][1] + red5[e][2] + red5[e][3];
  }
  __syncthreads();

  float lg[NEXP];
  #pragma unroll
  for (int e = 0; e < NEXP; e++) lg[e] = logits_s[e];
  int sel = 0; float best = lg[0];
  #pragma unroll
  for (int e = 1; e < NEXP; e++) if (lg[e] > best) { best = lg[e]; sel = e; }

  if (t == 0) {
    float s = 0.f, p[NEXP];
    #pragma unroll
    for (int e = 0; e < NEXP; e++) { p[e] = __expf(lg[e] - best); s += p[e]; }
    float inv = 1.0f / s;
    #pragma unroll
    for (int e = 0; e < NEXP; e++) atomicAdd(&accum[e], p[e] * inv);
    atomicAdd(&accum[NEXP + sel], 1.0f);
  }

  // ---- LoRA correction (block-uniform branch) ----
  float outv[8] = {0.f,0.f,0.f,0.f,0.f,0.f,0.f,0.f};
  if (sel > 0) {
    const int e = sel - 1;
    const float* A = LA + (size_t)e * RANK * H_DIM;
    float tp[RANK];
    #pragma unroll
    for (int r = 0; r < RANK; r++) {
      const float* ar = A + r * H_DIM + t * 8;
      float4 a0 = ((const float4*)ar)[0];
      float4 a1 = ((const float4*)ar)[1];
      tp[r] = xv[0]*a0.x + xv[1]*a0.y + xv[2]*a0.z + xv[3]*a0.w
            + xv[4]*a1.x + xv[5]*a1.y + xv[6]*a1.z + xv[7]*a1.w;
    }
    #pragma unroll
    for (int r = 0; r < RANK; r++)
      #pragma unroll
      for (int off = 32; off > 0; off >>= 1)
        tp[r] += __shfl_down(tp[r], off, 64);
    if (lane == 0) {
      #pragma unroll
      for (int r = 0; r < RANK; r++) tred[wid][r] = tp[r];
    }
    __syncthreads();
    if (t < RANK) tvec[t] = tred[0][t] + tred[1][t] + tred[2][t] + tred[3][t];
    __syncthreads();

    const float* Bm = LB + (size_t)e * H_DIM * RANK;
    #pragma unroll
    for (int j = 0; j < 8; j++) {
      int h = t * 8 + j;
      const float* brow = Bm + h * RANK;
      float s = 0.f;
      #pragma unroll
      for (int r = 0; r < RANK; r += 4) {
        float4 b = ((const float4*)(brow + r))[0];
        s += tvec[r]*b.x + tvec[r+1]*b.y + tvec[r+2]*b.z + tvec[r+3]*b.w;
      }
      outv[j] = LORA_SCALE * s;
    }
  }
  float4* dst = (float4*)(lora_out + (size_t)token * H_DIM + t * 8);
  dst[0] = make_float4(outv[0], outv[1], outv[2], outv[3]);
  dst[1] = make_float4(outv[4], outv[5], outv[6], outv[7]);
}

// ===========================================================================
// 8-phase GEMM kernels (T2 swizzle + T3/T4 counted vmcnt + T5 setprio).
//
// Common structure: BK=64, 512 threads = 8 waves, double-buffered LDS
// (128 KiB), one K-tile = 4 phases of {ds_read subtile; issue half-tile
// staging; s_barrier; lgkmcnt(0); setprio(1); 16 MFMA; setprio(0);
// [ph4: counted vmcnt]; s_barrier}.  Raw s_barrier (NOT __syncthreads —
// that drains vmcnt(0) and kills the pipeline); waitcnt asm carries a
// "memory" clobber so loads cannot hoist across the drain point.
//
// LDS chunk-XOR swizzle: row r of a [rows][64] bf16 tile stores global
// 16B-chunk g at slot g ^ ((r>>1)&7).  Staging keeps the global_load_lds
// dest linear (base + chunkidx*16) and pre-swizzles the GLOBAL source
// chunk; fragment reads apply the same XOR.  Lanes fr=0..15 then hit 8
// distinct 16B columns (2 rows each => 2-way, free) instead of one.
//
// vmcnt ledger (per wave, per K-tile t): issued ph1: 2 loads (t+1),
// ph2: 2 loads (t+1), ph4: 4 loads (t+2).  At ph4's wait point the
// outstanding queue is [4 (t+1, from t-1 ph4)][2][2 (t+1)][4 (t+2)]
// = 12, so vmcnt(4) drains exactly tile t+1 and leaves t+2's 4 loads
// in flight across the barrier.
//
// WAR safety: t+2's staging targets the buffer tile t computes from,
// but every wave's ds_reads of that region complete before that wave's
// MFMA issue (compiler lgkmcnt) and hence before the phase-end barrier
// that precedes the staging issue.
// ===========================================================================

// ---------------------------------------------------------------------------
// Kernel 2: act = gelu(X @ Wg^T) * (X @ Wu^T), fused, tile 256x128.
// A = X (256 rows), G = Wg (128 rows), U = Wu (128 rows); 8 waves 4Mx2N,
// per-wave 64x64 with two accumulators.
// Phases: 1) A(all)+G-lo reads, MFMA accg-lo   2) G-hi, MFMA accg-hi
//         3) U-lo, MFMA accu-lo                4) U-hi, MFMA accu-hi
// Staging: ph1 -> G(t+1), ph2 -> U(t+1), ph4 -> A both halves (t+2).
// ---------------------------------------------------------------------------
__global__ __launch_bounds__(512, 2) void gemm_gateup_kernel(
    const uint16_t* __restrict__ X,    // [T, H] bf16
    const uint16_t* __restrict__ Wg,   // [I, H] bf16
    const uint16_t* __restrict__ Wu,   // [I, H] bf16
    uint16_t* __restrict__ act)        // [T, I] bf16
{
  constexpr int K  = H_DIM;
  constexpr int NT = K / 64;                        // 32 K-tiles
  __shared__ __align__(16) uint16_t sA[2 * 16384];  // [buf][256][64]
  __shared__ __align__(16) uint16_t sG[2 * 8192];   // [buf][128][64]
  __shared__ __align__(16) uint16_t sU[2 * 8192];

  const int tid  = threadIdx.x;
  const int lane = tid & 63;
  const int wid  = tid >> 6;
  const int wr = wid >> 1;          // 0..3 -> M offset wr*64
  const int wc = wid & 1;           // 0..1 -> N offset wc*64
  const int fr = lane & 15;
  const int s4 = lane >> 4;

  // XCD-aware bijective swizzle (gridDim.x % 8 == 0)
  const int id  = blockIdx.x;
  const int cpx = gridDim.x >> 3;
  const int sid = (id & 7) * cpx + (id >> 3);
  const int bm  = sid >> 7;                          // I/128 = 128 N-tiles
  const int bn  = sid & 127;
  const int m0 = bm * 256;
  const int n0 = bn * 128;

  // staging: thread owns chunks (tid, tid+512) of each 1024-chunk half
  const int c0 = tid, c1 = tid + 512;
  const int r0 = c0 >> 3, q0 = (c0 & 7) ^ ((r0 >> 1) & 7);
  const int r1 = c1 >> 3, q1 = (c1 & 7) ^ ((r1 >> 1) & 7);

  const uint16_t* gA00 = X  + (size_t)(m0 + r0) * K + q0 * 8;
  const uint16_t* gA01 = X  + (size_t)(m0 + r1) * K + q1 * 8;
  const uint16_t* gA10 = X  + (size_t)(m0 + 128 + r0) * K + q0 * 8;
  const uint16_t* gA11 = X  + (size_t)(m0 + 128 + r1) * K + q1 * 8;
  const uint16_t* gG0  = Wg + (size_t)(n0 + r0) * K + q0 * 8;
  const uint16_t* gG1  = Wg + (size_t)(n0 + r1) * K + q1 * 8;
  const uint16_t* gU0  = Wu + (size_t)(n0 + r0) * K + q0 * 8;
  const uint16_t* gU1  = Wu + (size_t)(n0 + r1) * K + q1 * 8;

  auto stageA = [&](int tt) {   // 4 loads: both A halves
    uint16_t* d = sA + (tt & 1) * 16384;
    const size_t ko = (size_t)tt * 64;
    __builtin_amdgcn_global_load_lds((gv_t*)(gA00 + ko), (lv_t*)(d + c0 * 8), 16, 0, 0);
    __builtin_amdgcn_global_load_lds((gv_t*)(gA01 + ko), (lv_t*)(d + c1 * 8), 16, 0, 0);
    __builtin_amdgcn_global_load_lds((gv_t*)(gA10 + ko), (lv_t*)(d + 8192 + c0 * 8), 16, 0, 0);
    __builtin_amdgcn_global_load_lds((gv_t*)(gA11 + ko), (lv_t*)(d + 8192 + c1 * 8), 16, 0, 0);
  };
  auto stageG = [&](int tt) {   // 2 loads
    uint16_t* d = sG + (tt & 1) * 8192;
    const size_t ko = (size_t)tt * 64;
    __builtin_amdgcn_global_load_lds((gv_t*)(gG0 + ko), (lv_t*)(d + c0 * 8), 16, 0, 0);
    __builtin_amdgcn_global_load_lds((gv_t*)(gG1 + ko), (lv_t*)(d + c1 * 8), 16, 0, 0);
  };
  auto stageU = [&](int tt) {   // 2 loads
    uint16_t* d = sU + (tt & 1) * 8192;
    const size_t ko = (size_t)tt * 64;
    __builtin_amdgcn_global_load_lds((gv_t*)(gU0 + ko), (lv_t*)(d + c0 * 8), 16, 0, 0);
    __builtin_amdgcn_global_load_lds((gv_t*)(gU1 + ko), (lv_t*)(d + c1 * 8), 16, 0, 0);
  };

  // fragment LDS element offsets for kk=0; kk=1 is ^32 (chunk bit2 flip)
  int offA[4], offB[4];
  #pragma unroll
  for (int mi = 0; mi < 4; mi++) {
    int r = wr * 64 + mi * 16 + fr;
    offA[mi] = r * 64 + ((s4 ^ ((r >> 1) & 7)) * 8);
  }
  #pragma unroll
  for (int ni = 0; ni < 4; ni++) {
    int r = wc * 64 + ni * 16 + fr;
    offB[ni] = r * 64 + ((s4 ^ ((r >> 1) & 7)) * 8);
  }

  f32x4 accg[4][4], accu[4][4];
  #pragma unroll
  for (int i = 0; i < 4; i++)
    #pragma unroll
    for (int j = 0; j < 4; j++) {
      accg[i][j] = (f32x4){0.f, 0.f, 0.f, 0.f};
      accu[i][j] = (f32x4){0.f, 0.f, 0.f, 0.f};
    }

  // prologue: tile0 complete (8 loads) + A halves of tile1 (4 loads)
  stageA(0); stageG(0); stageU(0); stageA(1);
  asm volatile("s_waitcnt vmcnt(4)" ::: "memory");
  __builtin_amdgcn_s_barrier();
  asm volatile("" ::: "memory");

  #pragma unroll 2
  for (int t = 0; t < NT; ++t) {
    const uint16_t* a  = sA + (t & 1) * 16384;
    const uint16_t* gq = sG + (t & 1) * 8192;
    const uint16_t* uq = sU + (t & 1) * 8192;

    // ---------------- phase 1: A(all) + G-lo; stage G(t+1) ----------------
    bf16x8 af[4][2], b0[2][2];
    #pragma unroll
    for (int mi = 0; mi < 4; mi++) {
      af[mi][0] = *(const bf16x8*)(a + offA[mi]);
      af[mi][1] = *(const bf16x8*)(a + (offA[mi] ^ 32));
    }
    #pragma unroll
    for (int ni = 0; ni < 2; ni++) {
      b0[ni][0] = *(const bf16x8*)(gq + offB[ni]);
      b0[ni][1] = *(const bf16x8*)(gq + (offB[ni] ^ 32));
    }
    if (t + 1 < NT) stageG(t + 1);
    __builtin_amdgcn_s_barrier();
    asm volatile("s_waitcnt lgkmcnt(0)" ::: "memory");
    __builtin_amdgcn_s_setprio(1);
    #pragma unroll
    for (int mi = 0; mi < 4; mi++)
      #pragma unroll
      for (int ni = 0; ni < 2; ni++) {
        accg[mi][ni] = __builtin_amdgcn_mfma_f32_16x16x32_bf16(af[mi][0], b0[ni][0], accg[mi][ni], 0, 0, 0);
        accg[mi][ni] = __builtin_amdgcn_mfma_f32_16x16x32_bf16(af[mi][1], b0[ni][1], accg[mi][ni], 0, 0, 0);
      }
    __builtin_amdgcn_s_setprio(0);
    __builtin_amdgcn_s_barrier();
    asm volatile("" ::: "memory");

    // ---------------- phase 2: G-hi; stage U(t+1) ----------------
    bf16x8 b1[2][2];
    #pragma unroll
    for (int ni = 0; ni < 2; ni++) {
      b1[ni][0] = *(const bf16x8*)(gq + offB[2 + ni]);
      b1[ni][1] = *(const bf16x8*)(gq + (offB[2 + ni] ^ 32));
    }
    if (t + 1 < NT) stageU(t + 1);
    __builtin_amdgcn_s_barrier();
    asm volatile("s_waitcnt lgkmcnt(0)" ::: "memory");
    __builtin_amdgcn_s_setprio(1);
    #pragma unroll
    for (int mi = 0; mi < 4; mi++)
      #pragma unroll
      for (int ni = 0; ni < 2; ni++) {
        accg[mi][2 + ni] = __builtin_amdgcn_mfma_f32_16x16x32_bf16(af[mi][0], b1[ni][0], accg[mi][2 + ni], 0, 0, 0);
        accg[mi][2 + ni] = __builtin_amdgcn_mfma_f32_16x16x32_bf16(af[mi][1], b1[ni][1], accg[mi][2 + ni], 0, 0, 0);
      }
    __builtin_amdgcn_s_setprio(0);
    __builtin_amdgcn_s_barrier();
    asm volatile("" ::: "memory");

    // ---------------- phase 3: U-lo ----------------
    bf16x8 b2[2][2];
    #pragma unroll
    for (int ni = 0; ni < 2; ni++) {
      b2[ni][0] = *(const bf16x8*)(uq + offB[ni]);
      b2[ni][1] = *(const bf16x8*)(uq + (offB[ni] ^ 32));
    }
    __builtin_amdgcn_s_barrier();
    asm volatile("s_waitcnt lgkmcnt(0)" ::: "memory");
    __builtin_amdgcn_s_setprio(1);
    #pragma unroll
    for (int mi = 0; mi < 4; mi++)
      #pragma unroll
      for (int ni = 0; ni < 2; ni++) {
        accu[mi][ni] = __builtin_amdgcn_mfma_f32_16x16x32_bf16(af[mi][0], b2[ni][0], accu[mi][ni], 0, 0, 0);
        accu[mi][ni] = __builtin_amdgcn_mfma_f32_16x16x32_bf16(af[mi][1], b2[ni][1], accu[mi][ni], 0, 0, 0);
      }
    __builtin_amdgcn_s_setprio(0);
    __builtin_amdgcn_s_barrier();
    asm volatile("" ::: "memory");

    // ---------------- phase 4: U-hi; stage A(t+2); counted vmcnt ----------
    bf16x8 b3[2][2];
    #pragma unroll
    for (int ni = 0; ni < 2; ni++) {
      b3[ni][0] = *(const bf16x8*)(uq + offB[2 + ni]);
      b3[ni][1] = *(const bf16x8*)(uq + (offB[2 + ni] ^ 32));
    }
    if (t + 2 < NT) stageA(t + 2);
    __builtin_amdgcn_s_barrier();
    asm volatile("s_waitcnt lgkmcnt(0)" ::: "memory");
    __builtin_amdgcn_s_setprio(1);
    #pragma unroll
    for (int mi = 0; mi < 4; mi++)
      #pragma unroll
      for (int ni = 0; ni < 2; ni++) {
        accu[mi][2 + ni] = __builtin_amdgcn_mfma_f32_16x16x32_bf16(af[mi][0], b3[ni][0], accu[mi][2 + ni], 0, 0, 0);
        accu[mi][2 + ni] = __builtin_amdgcn_mfma_f32_16x16x32_bf16(af[mi][1], b3[ni][1], accu[mi][2 + ni], 0, 0, 0);
      }
    __builtin_amdgcn_s_setprio(0);
    if (t + 2 < NT) { asm volatile("s_waitcnt vmcnt(4)" ::: "memory"); }
    else            { asm volatile("s_waitcnt vmcnt(0)" ::: "memory"); }
    __builtin_amdgcn_s_barrier();
    asm volatile("" ::: "memory");
  }

  // epilogue: C/D layout col=lane&15, row=(lane>>4)*4+reg  [m89-verified]
  const int rbase = s4 * 4;
  const int cbase = fr;
  #pragma unroll
  for (int mi = 0; mi < 4; mi++)
    #pragma unroll
    for (int ni = 0; ni < 4; ni++)
      #pragma unroll
      for (int i = 0; i < 4; i++) {
        int row = m0 + wr * 64 + mi * 16 + rbase + i;
        int col = n0 + wc * 64 + ni * 16 + cbase;
        float g = accg[mi][ni][i];
        float u = accu[mi][ni][i];
        act[(size_t)row * I_DIM + col] = f2bf(gelu_fast(g) * u);
      }
}

// ---------------------------------------------------------------------------
// Kernel 3: out = act @ Wd^T + lora  (Wd stored [H, I] == B^T form)
// Standard 256x256 template: 8 waves 2Mx4N, per-wave 128x64.
// Phases: 1) A-lo + B-lo, MFMA Q00   2) B-hi, MFMA Q01
//         3) A-hi, MFMA Q10          4) MFMA Q11 (regs only)
// Staging: ph1 -> B-h0(t+1), ph2 -> B-h1(t+1), ph4 -> A both halves (t+2).
// ---------------------------------------------------------------------------
__global__ __launch_bounds__(512, 2) void gemm_down_kernel(
    const uint16_t* __restrict__ Act,  // [T, I] bf16
    const uint16_t* __restrict__ Wd,   // [H, I] bf16
    float* __restrict__ out)           // [T, H] fp32 (holds lora on entry)
{
  constexpr int K  = I_DIM;
  constexpr int NT = K / 64;                         // 256 K-tiles
  __shared__ __align__(16) uint16_t sA[2 * 16384];   // [buf][256][64]
  __shared__ __align__(16) uint16_t sB[2 * 16384];

  const int tid  = threadIdx.x;
  const int lane = tid & 63;
  const int wid  = tid >> 6;
  const int wr = wid >> 2;          // 0..1 -> M offset wr*128
  const int wc = wid & 3;           // 0..3 -> N offset wc*64
  const int fr = lane & 15;
  const int s4 = lane >> 4;

  const int id  = blockIdx.x;
  const int cpx = gridDim.x >> 3;
  const int sid = (id & 7) * cpx + (id >> 3);
  const int bm  = sid >> 3;                          // H/256 = 8 N-tiles
  const int bn  = sid & 7;
  const int m0 = bm * 256;
  const int n0 = bn * 256;

  const int c0 = tid, c1 = tid + 512;
  const int r0 = c0 >> 3, q0 = (c0 & 7) ^ ((r0 >> 1) & 7);
  const int r1 = c1 >> 3, q1 = (c1 & 7) ^ ((r1 >> 1) & 7);

  const uint16_t* gA00 = Act + (size_t)(m0 + r0) * K + q0 * 8;
  const uint16_t* gA01 = Act + (size_t)(m0 + r1) * K + q1 * 8;
  const uint16_t* gA10 = Act + (size_t)(m0 + 128 + r0) * K + q0 * 8;
  const uint16_t* gA11 = Act + (size_t)(m0 + 128 + r1) * K + q1 * 8;
  const uint16_t* gB00 = Wd  + (size_t)(n0 + r0) * K + q0 * 8;
  const uint16_t* gB01 = Wd  + (size_t)(n0 + r1) * K + q1 * 8;
  const uint16_t* gB10 = Wd  + (size_t)(n0 + 128 + r0) * K + q0 * 8;
  const uint16_t* gB11 = Wd  + (size_t)(n0 + 128 + r1) * K + q1 * 8;

  auto stageA = [&](int tt) {   // 4 loads
    uint16_t* d = sA + (tt & 1) * 16384;
    const size_t ko = (size_t)tt * 64;
    __builtin_amdgcn_global_load_lds((gv_t*)(gA00 + ko), (lv_t*)(d + c0 * 8), 16, 0, 0);
    __builtin_amdgcn_global_load_lds((gv_t*)(gA01 + ko), (lv_t*)(d + c1 * 8), 16, 0, 0);
    __builtin_amdgcn_global_load_lds((gv_t*)(gA10 + ko), (lv_t*)(d + 8192 + c0 * 8), 16, 0, 0);
    __builtin_amdgcn_global_load_lds((gv_t*)(gA11 + ko), (lv_t*)(d + 8192 + c1 * 8), 16, 0, 0);
  };
  auto stageB0 = [&](int tt) {  // 2 loads (B rows 0..127)
    uint16_t* d = sB + (tt & 1) * 16384;
    const size_t ko = (size_t)tt * 64;
    __builtin_amdgcn_global_load_lds((gv_t*)(gB00 + ko), (lv_t*)(d + c0 * 8), 16, 0, 0);
    __builtin_amdgcn_global_load_lds((gv_t*)(gB01 + ko), (lv_t*)(d + c1 * 8), 16, 0, 0);
  };
  auto stageB1 = [&](int tt) {  // 2 loads (B rows 128..255)
    uint16_t* d = sB + (tt & 1) * 16384;
    const size_t ko = (size_t)tt * 64;
    __builtin_amdgcn_global_load_lds((gv_t*)(gB10 + ko), (lv_t*)(d + 8192 + c0 * 8), 16, 0, 0);
    __builtin_amdgcn_global_load_lds((gv_t*)(gB11 + ko), (lv_t*)(d + 8192 + c1 * 8), 16, 0, 0);
  };

  int offA[8], offB[4];
  #pragma unroll
  for (int mi = 0; mi < 8; mi++) {
    int r = wr * 128 + mi * 16 + fr;
    offA[mi] = r * 64 + ((s4 ^ ((r >> 1) & 7)) * 8);
  }
  #pragma unroll
  for (int ni = 0; ni < 4; ni++) {
    int r = wc * 64 + ni * 16 + fr;
    offB[ni] = r * 64 + ((s4 ^ ((r >> 1) & 7)) * 8);
  }

  f32x4 acc[8][4];
  #pragma unroll
  for (int i = 0; i < 8; i++)
    #pragma unroll
    for (int j = 0; j < 4; j++) acc[i][j] = (f32x4){0.f, 0.f, 0.f, 0.f};

  stageA(0); stageB0(0); stageB1(0); stageA(1);
  asm volatile("s_waitcnt vmcnt(4)" ::: "memory");
  __builtin_amdgcn_s_barrier();
  asm volatile("" ::: "memory");

  #pragma unroll 2
  for (int t = 0; t < NT; ++t) {
    const uint16_t* a = sA + (t & 1) * 16384;
    const uint16_t* b = sB + (t & 1) * 16384;

    // ---------------- phase 1: A-lo + B-lo; stage B-h0(t+1) ---------------
    bf16x8 al[4][2], bl[2][2];
    #pragma unroll
    for (int mi = 0; mi < 4; mi++) {
      al[mi][0] = *(const bf16x8*)(a + offA[mi]);
      al[mi][1] = *(const bf16x8*)(a + (offA[mi] ^ 32));
    }
    #pragma unroll
    for (int ni = 0; ni < 2; ni++) {
      bl[ni][0] = *(const bf16x8*)(b + offB[ni]);
      bl[ni][1] = *(const bf16x8*)(b + (offB[ni] ^ 32));
    }
    if (t + 1 < NT) stageB0(t + 1);
    __builtin_amdgcn_s_barrier();
    asm volatile("s_waitcnt lgkmcnt(0)" ::: "memory");
    __builtin_amdgcn_s_setprio(1);
    #pragma unroll
    for (int mi = 0; mi < 4; mi++)
      #pragma unroll
      for (int ni = 0; ni < 2; ni++) {
        acc[mi][ni] = __builtin_amdgcn_mfma_f32_16x16x32_bf16(al[mi][0], bl[ni][0], acc[mi][ni], 0, 0, 0);
        acc[mi][ni] = __builtin_amdgcn_mfma_f32_16x16x32_bf16(al[mi][1], bl[ni][1], acc[mi][ni], 0, 0, 0);
      }
    __builtin_amdgcn_s_setprio(0);
    __builtin_amdgcn_s_barrier();
    asm volatile("" ::: "memory");

    // ---------------- phase 2: B-hi; stage B-h1(t+1) ---------------
    bf16x8 bh[2][2];
    #pragma unroll
    for (int ni = 0; ni < 2; ni++) {
      bh[ni][0] = *(const bf16x8*)(b + offB[2 + ni]);
      bh[ni][1] = *(const bf16x8*)(b + (offB[2 + ni] ^ 32));
    }
    if (t + 1 < NT) stageB1(t + 1);
    __builtin_amdgcn_s_barrier();
    asm volatile("s_waitcnt lgkmcnt(0)" ::: "memory");
    __builtin_amdgcn_s_setprio(1);
    #pragma unroll
    for (int mi = 0; mi < 4; mi++)
      #pragma unroll
      for (int ni = 0; ni < 2; ni++) {
        acc[mi][2 + ni] = __builtin_amdgcn_mfma_f32_16x16x32_bf16(al[mi][0], bh[ni][0], acc[mi][2 + ni], 0, 0, 0);
        acc[mi][2 + ni] = __builtin_amdgcn_mfma_f32_16x16x32_bf16(al[mi][1], bh[ni][1], acc[mi][2 + ni], 0, 0, 0);
      }
    __builtin_amdgcn_s_setprio(0);
    __builtin_amdgcn_s_barrier();
    asm volatile("" ::: "memory");

    // ---------------- phase 3: A-hi ---------------
    bf16x8 ah[4][2];
    #pragma unroll
    for (int mi = 0; mi < 4; mi++) {
      ah[mi][0] = *(const bf16x8*)(a + offA[4 + mi]);
      ah[mi][1] = *(const bf16x8*)(a + (offA[4 + mi] ^ 32));
    }
    __builtin_amdgcn_s_barrier();
    asm volatile("s_waitcnt lgkmcnt(0)" ::: "memory");
    __builtin_amdgcn_s_setprio(1);
    #pragma unroll
    for (int mi = 0; mi < 4; mi++)
      #pragma unroll
      for (int ni = 0; ni < 2; ni++) {
        acc[4 + mi][ni] = __builtin_amdgcn_mfma_f32_16x16x32_bf16(ah[mi][0], bl[ni][0], acc[4 + mi][ni], 0, 0, 0);
        acc[4 + mi][ni] = __builtin_amdgcn_mfma_f32_16x16x32_bf16(ah[mi][1], bl[ni][1], acc[4 + mi][ni], 0, 0, 0);
      }
    __builtin_amdgcn_s_setprio(0);
    __builtin_amdgcn_s_barrier();
    asm volatile("" ::: "memory");

    // ---------------- phase 4: regs only; stage A(t+2); counted vmcnt -----
    if (t + 2 < NT) stageA(t + 2);
    __builtin_amdgcn_s_barrier();
    __builtin_amdgcn_s_setprio(1);
    #pragma unroll
    for (int mi = 0; mi < 4; mi++)
      #pragma unroll
      for (int ni = 0; ni < 2; ni++) {
        acc[4 + mi][2 + ni] = __builtin_amdgcn_mfma_f32_16x16x32_bf16(ah[mi][0], bh[ni][0], acc[4 + mi][2 + ni], 0, 0, 0);
        acc[4 + mi][2 + ni] = __builtin_amdgcn_mfma_f32_16x16x32_bf16(ah[mi][1], bh[ni][1], acc[4 + mi][2 + ni], 0, 0, 0);
      }
    __builtin_amdgcn_s_setprio(0);
    if (t + 2 < NT) { asm volatile("s_waitcnt vmcnt(4)" ::: "memory"); }
    else            { asm volatile("s_waitcnt vmcnt(0)" ::: "memory"); }
    __builtin_amdgcn_s_barrier();
    asm volatile("" ::: "memory");
  }

  const int rbase = s4 * 4;
  const int cbase = fr;
  #pragma unroll
  for (int mi = 0; mi < 8; mi++)
    #pragma unroll
    for (int ni = 0; ni < 4; ni++)
      #pragma unroll
      for (int i = 0; i < 4; i++) {
        int row = m0 + wr * 128 + mi * 16 + rbase + i;
        int col = n0 + wc * 64 + ni * 16 + cbase;
        size_t idx = (size_t)row * H_DIM + col;
        out[idx] = acc[mi][ni][i] + out[idx];
      }
}

// ---------------------------------------------------------------------------
// Kernel 4: aux loss scalar (fp32)
// ---------------------------------------------------------------------------
__global__ void aux_kernel(const float* __restrict__ accum,
                           float* __restrict__ out_aux)
{
  if (threadIdx.x == 0 && blockIdx.x == 0) {
    float s = 0.f;
    #pragma unroll
    for (int e = 0; e < NEXP; e++)
      s += (accum[e] / (float)T_TOKENS) * (accum[NEXP + e] / (float)T_TOKENS);
    out_aux[0] = s * (float)NEXP * 0.01f;
  }
}

// ---------------------------------------------------------------------------
extern "C" void kernel_launch(void* const* d_in, const int* in_sizes, int n_in,
                              void* d_out, int out_size, void* d_ws, size_t ws_size,
                              hipStream_t stream) {
  const float* X  = (const float*)d_in[0];  // hidden_states [4,2048,2048] fp32
  const float* RW = (const float*)d_in[1];  // router_w [5,2048]
  const float* Wg = (const float*)d_in[2];  // gate_w [16384,2048]
  const float* Wu = (const float*)d_in[3];  // up_w [16384,2048]
  const float* Wd = (const float*)d_in[4];  // down_w [2048,16384]
  const float* LA = (const float*)d_in[5];  // lora_A [4,16,2048]
  const float* LB = (const float*)d_in[6];  // lora_B [4,2048,16]
  float* out = (float*)d_out;               // [4,2048,2048] fp32 + 1 aux

  char* ws = (char*)d_ws;
  uint16_t* Xb    = (uint16_t*)(ws);                         // 32 MiB bf16 [T,H]
  uint16_t* Wgb   = (uint16_t*)(ws + (size_t)32  * 1048576); // 64 MiB bf16 [I,H]
  uint16_t* Wub   = (uint16_t*)(ws + (size_t)96  * 1048576); // 64 MiB
  uint16_t* Wdb   = (uint16_t*)(ws + (size_t)160 * 1048576); // 64 MiB [H,I]
  uint16_t* act   = (uint16_t*)(ws + (size_t)224 * 1048576); // 256 MiB bf16 [T,I]
  float*    accum = (float*)   (ws + (size_t)480 * 1048576); // 16 floats

  hipMemsetAsync(accum, 0, 16 * sizeof(float), stream);

  const int nW = I_DIM * H_DIM;
  cvt_kernel<<<nW / 8 / 256, 256, 0, stream>>>(Wg, Wgb, nW / 8);
  cvt_kernel<<<nW / 8 / 256, 256, 0, stream>>>(Wu, Wub, nW / 8);
  cvt_kernel<<<nW / 8 / 256, 256, 0, stream>>>(Wd, Wdb, nW / 8);

  router_lora_kernel<<<T_TOKENS, 256, 0, stream>>>(X, RW, LA, LB, out, Xb, accum);
  gemm_gateup_kernel<<<(T_TOKENS / 256) * (I_DIM / 128), 512, 0, stream>>>(Xb, Wgb, Wub, act);
  gemm_down_kernel<<<(T_TOKENS / 256) * (H_DIM / 256), 512, 0, stream>>>(act, Wdb, out);
  aux_kernel<<<1, 64, 0, stream>>>(accum, out + (size_t)T_TOKENS * H_DIM);
}

// Round 2
// 2421.279 us; speedup vs baseline: 1.2597x; 1.1100x over previous
//
#include <hip/hip_runtime.h>
#include <stdint.h>
#include <math.h>

#define T_TOKENS 8192
#define H_DIM    2048
#define I_DIM    16384
#define NEXP     5
#define RANK     16
#define LORA_SCALE 2.0f
#define NBUCK    64

typedef __attribute__((ext_vector_type(8))) short bf16x8;   // 8 bf16 in 4 VGPRs
typedef __attribute__((ext_vector_type(4))) float f32x4;

typedef const __attribute__((address_space(1))) void gv_t;  // global
typedef __attribute__((address_space(3))) void lv_t;        // LDS

__device__ __forceinline__ uint16_t f2bf(float f) {
  union { uint32_t u; float f; } v; v.f = f;
  uint32_t u = v.u;
  return (uint16_t)((u + 0x7fffu + ((u >> 16) & 1u)) >> 16);
}
__device__ __forceinline__ uint32_t pack2(float lo, float hi) {
  return (uint32_t)f2bf(lo) | ((uint32_t)f2bf(hi) << 16);
}
// gelu_tanh(x) == x * sigmoid(2*0.7978845608*(x + 0.044715 x^3)); __expf -> v_exp_f32
__device__ __forceinline__ float gelu_fast(float x) {
  float x3 = x * x * x;
  float z = 1.5957691216057308f * (x + 0.044715f * x3);
  return x / (1.0f + __expf(-z));
}

// ---------------------------------------------------------------------------
// Kernel 0: fp32 -> bf16 conversion (8 elements / thread)
// ---------------------------------------------------------------------------
__global__ __launch_bounds__(256) void cvt_kernel(
    const float* __restrict__ src, uint16_t* __restrict__ dst, int n8)
{
  int i = blockIdx.x * 256 + threadIdx.x;
  if (i >= n8) return;
  float4 a = ((const float4*)src)[2 * i];
  float4 b = ((const float4*)src)[2 * i + 1];
  uint4 o;
  o.x = pack2(a.x, a.y);
  o.y = pack2(a.z, a.w);
  o.z = pack2(b.x, b.y);
  o.w = pack2(b.z, b.w);
  ((uint4*)dst)[i] = o;
}

// ---------------------------------------------------------------------------
// Kernel 1: router logits -> softmax stats + rank-16 LoRA (fp32 in).
// Also emits the bf16 copy of X. One block (256 threads) per token.
// Atomics bucketed by blockIdx&63 to kill same-line serialization.
// ---------------------------------------------------------------------------
__global__ __launch_bounds__(256) void router_lora_kernel(
    const float* __restrict__ X,     // [T, H] fp32
    const float* __restrict__ RW,    // [5, H]
    const float* __restrict__ LA,    // [4, 16, H]
    const float* __restrict__ LB,    // [4, H, 16]
    float* __restrict__ lora_out,    // [T, H] fp32  (== d_out)
    uint16_t* __restrict__ Xb,       // [T, H] bf16
    float* __restrict__ accum)       // [10*NBUCK] fp32
{
  const int token = blockIdx.x;
  const int t = threadIdx.x;
  const int lane = t & 63, wid = t >> 6;

  __shared__ float red5[NEXP][4];
  __shared__ float logits_s[NEXP];
  __shared__ float tred[4][RANK];
  __shared__ float tvec[RANK];

  const float* x = X + (size_t)token * H_DIM;
  float4 xa = ((const float4*)x)[2 * t];
  float4 xb = ((const float4*)x)[2 * t + 1];
  float xv[8] = {xa.x, xa.y, xa.z, xa.w, xb.x, xb.y, xb.z, xb.w};

  // bf16 copy of X
  {
    uint4 o;
    o.x = pack2(xv[0], xv[1]);
    o.y = pack2(xv[2], xv[3]);
    o.z = pack2(xv[4], xv[5]);
    o.w = pack2(xv[6], xv[7]);
    ((uint4*)(Xb + (size_t)token * H_DIM))[t] = o;
  }

  // ---- logits ----
  float part[NEXP];
  #pragma unroll
  for (int e = 0; e < NEXP; e++) {
    const float* r = RW + e * H_DIM + t * 8;
    float4 ra = ((const float4*)r)[0];
    float4 rb = ((const float4*)r)[1];
    part[e] = xv[0]*ra.x + xv[1]*ra.y + xv[2]*ra.z + xv[3]*ra.w
            + xv[4]*rb.x + xv[5]*rb.y + xv[6]*rb.z + xv[7]*rb.w;
  }
  #pragma unroll
  for (int e = 0; e < NEXP; e++)
    #pragma unroll
    for (int off = 32; off > 0; off >>= 1)
      part[e] += __shfl_down(part[e], off, 64);
  if (lane == 0) {
    #pragma unroll
    for (int e = 0; e < NEXP; e++) red5[e][wid] = part[e];
  }
  __syncthreads();
  if (t == 0) {
    #pragma unroll
    for (int e = 0; e < NEXP; e++)
      logits_s[e] = red5[e][0] + red5[e][1] + red5[e][2] + red5[e][3];
  }
  __syncthreads();

  float lg[NEXP];
  #pragma unroll
  for (int e = 0; e < NEXP; e++) lg[e] = logits_s[e];
  int sel = 0; float best = lg[0];
  #pragma unroll
  for (int e = 1; e < NEXP; e++) if (lg[e] > best) { best = lg[e]; sel = e; }

  if (t == 0) {
    const int buck = blockIdx.x & (NBUCK - 1);
    float s = 0.f, p[NEXP];
    #pragma unroll
    for (int e = 0; e < NEXP; e++) { p[e] = __expf(lg[e] - best); s += p[e]; }
    float inv = 1.0f / s;
    #pragma unroll
    for (int e = 0; e < NEXP; e++) atomicAdd(&accum[e * NBUCK + buck], p[e] * inv);
    atomicAdd(&accum[(NEXP + sel) * NBUCK + buck], 1.0f);
  }

  // ---- LoRA correction (block-uniform branch) ----
  float outv[8] = {0.f,0.f,0.f,0.f,0.f,0.f,0.f,0.f};
  if (sel > 0) {
    const int e = sel - 1;
    const float* A = LA + (size_t)e * RANK * H_DIM;
    float tp[RANK];
    #pragma unroll
    for (int r = 0; r < RANK; r++) {
      const float* ar = A + r * H_DIM + t * 8;
      float4 a0 = ((const float4*)ar)[0];
      float4 a1 = ((const float4*)ar)[1];
      tp[r] = xv[0]*a0.x + xv[1]*a0.y + xv[2]*a0.z + xv[3]*a0.w
            + xv[4]*a1.x + xv[5]*a1.y + xv[6]*a1.z + xv[7]*a1.w;
    }
    #pragma unroll
    for (int r = 0; r < RANK; r++)
      #pragma unroll
      for (int off = 32; off > 0; off >>= 1)
        tp[r] += __shfl_down(tp[r], off, 64);
    if (lane == 0) {
      #pragma unroll
      for (int r = 0; r < RANK; r++) tred[wid][r] = tp[r];
    }
    __syncthreads();
    if (t < RANK) tvec[t] = tred[0][t] + tred[1][t] + tred[2][t] + tred[3][t];
    __syncthreads();

    const float* Bm = LB + (size_t)e * H_DIM * RANK;
    #pragma unroll
    for (int j = 0; j < 8; j++) {
      int h = t * 8 + j;
      const float* brow = Bm + h * RANK;
      float s = 0.f;
      #pragma unroll
      for (int r = 0; r < RANK; r += 4) {
        float4 b = ((const float4*)(brow + r))[0];
        s += tvec[r]*b.x + tvec[r+1]*b.y + tvec[r+2]*b.z + tvec[r+3]*b.w;
      }
      outv[j] = LORA_SCALE * s;
    }
  }
  float4* dst = (float4*)(lora_out + (size_t)token * H_DIM + t * 8);
  dst[0] = make_float4(outv[0], outv[1], outv[2], outv[3]);
  dst[1] = make_float4(outv[4], outv[5], outv[6], outv[7]);
}

// ===========================================================================
// GEMM kernels — 2 barriers per K-tile, reads overlapped with MFMA.
//
// Per K-tile: {read frags of the t+2-staged operand (8 ds_read_b128);
// stage next-tile other-buffer operands; lgkmcnt(0); s_barrier; stage
// t+2 operand into current buffer (now safe); read all remaining frags;
// 64 MFMA (compiler's counted lgkmcnt overlaps the reads under MFMA);
// counted vmcnt; s_barrier}.  No per-phase barriers: waves skew within
// the tile so LDS reads and MFMA run concurrently across waves instead
// of serializing in lockstep bursts (the round-1 42% MfmaUtil cause).
//
// Hazard ledger:
//  - reads of buf[cur] only after end-barrier of t-1 (post-vmcnt drain,
//    all waves' staging landed chip-wide).
//  - same-buffer t+2 staging issued only after lgkmcnt(0)+barrier drains
//    ALL waves' reads of that operand region.
//  - other-buffer t+1 staging: its region was last read in tile t-1 and
//    those reads completed before B2(t-1) (consumed by MFMA), so issuing
//    after B2(t-1) is WAR-safe.
//  - vmcnt(4) at tile end: outstanding = [t+1-stage:8][t+2-stage:4] = 12,
//    drains tile t+1 entirely, leaves t+2's 4 loads in flight.
//
// LDS chunk-XOR swizzle unchanged from round 1 (verified, 0 conflicts).
// ===========================================================================

// ---------------------------------------------------------------------------
// Kernel 2: act = gelu(X @ Wg^T) * (X @ Wu^T), fused, tile 256x128.
// 8 waves 4Mx2N, per-wave 64x64 with g and u accumulators.
// ---------------------------------------------------------------------------
__global__ __launch_bounds__(512, 2) void gemm_gateup_kernel(
    const uint16_t* __restrict__ X,    // [T, H] bf16
    const uint16_t* __restrict__ Wg,   // [I, H] bf16
    const uint16_t* __restrict__ Wu,   // [I, H] bf16
    uint16_t* __restrict__ act)        // [T, I] bf16
{
  constexpr int K  = H_DIM;
  constexpr int NT = K / 64;                        // 32 K-tiles
  __shared__ __align__(16) uint16_t sA[2 * 16384];  // [buf][256][64]
  __shared__ __align__(16) uint16_t sG[2 * 8192];   // [buf][128][64]
  __shared__ __align__(16) uint16_t sU[2 * 8192];

  const int tid  = threadIdx.x;
  const int lane = tid & 63;
  const int wid  = tid >> 6;
  const int wr = wid >> 1;          // 0..3 -> M offset wr*64
  const int wc = wid & 1;           // 0..1 -> N offset wc*64
  const int fr = lane & 15;
  const int s4 = lane >> 4;

  // XCD-aware bijective swizzle (gridDim.x % 8 == 0)
  const int id  = blockIdx.x;
  const int cpx = gridDim.x >> 3;
  const int sid = (id & 7) * cpx + (id >> 3);
  const int bm  = sid >> 7;                          // I/128 = 128 N-tiles
  const int bn  = sid & 127;
  const int m0 = bm * 256;
  const int n0 = bn * 128;

  // staging: thread owns chunks (tid, tid+512) of each 1024-chunk half
  const int c0 = tid, c1 = tid + 512;
  const int r0 = c0 >> 3, q0 = (c0 & 7) ^ ((r0 >> 1) & 7);
  const int r1 = c1 >> 3, q1 = (c1 & 7) ^ ((r1 >> 1) & 7);

  const uint16_t* gA00 = X  + (size_t)(m0 + r0) * K + q0 * 8;
  const uint16_t* gA01 = X  + (size_t)(m0 + r1) * K + q1 * 8;
  const uint16_t* gA10 = X  + (size_t)(m0 + 128 + r0) * K + q0 * 8;
  const uint16_t* gA11 = X  + (size_t)(m0 + 128 + r1) * K + q1 * 8;
  const uint16_t* gG0  = Wg + (size_t)(n0 + r0) * K + q0 * 8;
  const uint16_t* gG1  = Wg + (size_t)(n0 + r1) * K + q1 * 8;
  const uint16_t* gU0  = Wu + (size_t)(n0 + r0) * K + q0 * 8;
  const uint16_t* gU1  = Wu + (size_t)(n0 + r1) * K + q1 * 8;

  auto stageA = [&](int tt) {   // 4 loads: both A halves
    uint16_t* d = sA + (tt & 1) * 16384;
    const size_t ko = (size_t)tt * 64;
    __builtin_amdgcn_global_load_lds((gv_t*)(gA00 + ko), (lv_t*)(d + c0 * 8), 16, 0, 0);
    __builtin_amdgcn_global_load_lds((gv_t*)(gA01 + ko), (lv_t*)(d + c1 * 8), 16, 0, 0);
    __builtin_amdgcn_global_load_lds((gv_t*)(gA10 + ko), (lv_t*)(d + 8192 + c0 * 8), 16, 0, 0);
    __builtin_amdgcn_global_load_lds((gv_t*)(gA11 + ko), (lv_t*)(d + 8192 + c1 * 8), 16, 0, 0);
  };
  auto stageG = [&](int tt) {   // 2 loads
    uint16_t* d = sG + (tt & 1) * 8192;
    const size_t ko = (size_t)tt * 64;
    __builtin_amdgcn_global_load_lds((gv_t*)(gG0 + ko), (lv_t*)(d + c0 * 8), 16, 0, 0);
    __builtin_amdgcn_global_load_lds((gv_t*)(gG1 + ko), (lv_t*)(d + c1 * 8), 16, 0, 0);
  };
  auto stageU = [&](int tt) {   // 2 loads
    uint16_t* d = sU + (tt & 1) * 8192;
    const size_t ko = (size_t)tt * 64;
    __builtin_amdgcn_global_load_lds((gv_t*)(gU0 + ko), (lv_t*)(d + c0 * 8), 16, 0, 0);
    __builtin_amdgcn_global_load_lds((gv_t*)(gU1 + ko), (lv_t*)(d + c1 * 8), 16, 0, 0);
  };

  // fragment LDS element offsets for kk=0; kk=1 is ^32 (chunk bit2 flip)
  int offA[4], offB[4];
  #pragma unroll
  for (int mi = 0; mi < 4; mi++) {
    int r = wr * 64 + mi * 16 + fr;
    offA[mi] = r * 64 + ((s4 ^ ((r >> 1) & 7)) * 8);
  }
  #pragma unroll
  for (int ni = 0; ni < 4; ni++) {
    int r = wc * 64 + ni * 16 + fr;
    offB[ni] = r * 64 + ((s4 ^ ((r >> 1) & 7)) * 8);
  }

  f32x4 accg[4][4], accu[4][4];
  #pragma unroll
  for (int i = 0; i < 4; i++)
    #pragma unroll
    for (int j = 0; j < 4; j++) {
      accg[i][j] = (f32x4){0.f, 0.f, 0.f, 0.f};
      accu[i][j] = (f32x4){0.f, 0.f, 0.f, 0.f};
    }

  // prologue: tile0 complete (8 loads) + A of tile1 (4 loads)
  stageA(0); stageG(0); stageU(0); stageA(1);
  asm volatile("s_waitcnt vmcnt(4)" ::: "memory");
  __builtin_amdgcn_s_barrier();
  asm volatile("" ::: "memory");

  #pragma unroll 2
  for (int t = 0; t < NT; ++t) {
    const uint16_t* a  = sA + (t & 1) * 16384;
    const uint16_t* gq = sG + (t & 1) * 8192;
    const uint16_t* uq = sU + (t & 1) * 8192;

    // ---- A fragment reads (must drain before A(t+2) same-buffer staging)
    bf16x8 af[4][2];
    #pragma unroll
    for (int mi = 0; mi < 4; mi++) {
      af[mi][0] = *(const bf16x8*)(a + offA[mi]);
      af[mi][1] = *(const bf16x8*)(a + (offA[mi] ^ 32));
    }
    // stage next tile's G,U into the other buffer (WAR-safe post B2(t-1))
    if (t + 1 < NT) { stageG(t + 1); stageU(t + 1); }
    asm volatile("s_waitcnt lgkmcnt(0)" ::: "memory");
    __builtin_amdgcn_s_barrier();                     // all waves' A reads done
    asm volatile("" ::: "memory");
    if (t + 2 < NT) stageA(t + 2);                    // overwrite sA[cur]

    // ---- remaining fragment reads; MFMAs overlap the reads ----
    bf16x8 gf[4][2], uf[4][2];
    #pragma unroll
    for (int ni = 0; ni < 4; ni++) {
      gf[ni][0] = *(const bf16x8*)(gq + offB[ni]);
      gf[ni][1] = *(const bf16x8*)(gq + (offB[ni] ^ 32));
    }
    #pragma unroll
    for (int ni = 0; ni < 4; ni++) {
      uf[ni][0] = *(const bf16x8*)(uq + offB[ni]);
      uf[ni][1] = *(const bf16x8*)(uq + (offB[ni] ^ 32));
    }
    __builtin_amdgcn_s_setprio(1);
    #pragma unroll
    for (int mi = 0; mi < 4; mi++)
      #pragma unroll
      for (int ni = 0; ni < 4; ni++) {
        accg[mi][ni] = __builtin_amdgcn_mfma_f32_16x16x32_bf16(af[mi][0], gf[ni][0], accg[mi][ni], 0, 0, 0);
        accg[mi][ni] = __builtin_amdgcn_mfma_f32_16x16x32_bf16(af[mi][1], gf[ni][1], accg[mi][ni], 0, 0, 0);
      }
    #pragma unroll
    for (int mi = 0; mi < 4; mi++)
      #pragma unroll
      for (int ni = 0; ni < 4; ni++) {
        accu[mi][ni] = __builtin_amdgcn_mfma_f32_16x16x32_bf16(af[mi][0], uf[ni][0], accu[mi][ni], 0, 0, 0);
        accu[mi][ni] = __builtin_amdgcn_mfma_f32_16x16x32_bf16(af[mi][1], uf[ni][1], accu[mi][ni], 0, 0, 0);
      }
    __builtin_amdgcn_s_setprio(0);

    if (t + 2 < NT) { asm volatile("s_waitcnt vmcnt(4)" ::: "memory"); }
    else            { asm volatile("s_waitcnt vmcnt(0)" ::: "memory"); }
    __builtin_amdgcn_s_barrier();
    asm volatile("" ::: "memory");
  }

  // epilogue: C/D layout col=lane&15, row=(lane>>4)*4+reg  [m89-verified]
  const int rbase = s4 * 4;
  const int cbase = fr;
  #pragma unroll
  for (int mi = 0; mi < 4; mi++)
    #pragma unroll
    for (int ni = 0; ni < 4; ni++)
      #pragma unroll
      for (int i = 0; i < 4; i++) {
        int row = m0 + wr * 64 + mi * 16 + rbase + i;
        int col = n0 + wc * 64 + ni * 16 + cbase;
        float g = accg[mi][ni][i];
        float u = accu[mi][ni][i];
        act[(size_t)row * I_DIM + col] = f2bf(gelu_fast(g) * u);
      }
}

// ---------------------------------------------------------------------------
// Kernel 3: out = act @ Wd^T + lora  (Wd stored [H, I] == B^T form)
// 256x256 tile, 8 waves 2Mx4N, per-wave 128x64.  B (8 frag reads) is the
// same-buffer t+2-staged operand -> shortest serialized burst.
// ---------------------------------------------------------------------------
__global__ __launch_bounds__(512, 2) void gemm_down_kernel(
    const uint16_t* __restrict__ Act,  // [T, I] bf16
    const uint16_t* __restrict__ Wd,   // [H, I] bf16
    float* __restrict__ out)           // [T, H] fp32 (holds lora on entry)
{
  constexpr int K  = I_DIM;
  constexpr int NT = K / 64;                         // 256 K-tiles
  __shared__ __align__(16) uint16_t sA[2 * 16384];   // [buf][256][64]
  __shared__ __align__(16) uint16_t sB[2 * 16384];

  const int tid  = threadIdx.x;
  const int lane = tid & 63;
  const int wid  = tid >> 6;
  const int wr = wid >> 2;          // 0..1 -> M offset wr*128
  const int wc = wid & 3;           // 0..3 -> N offset wc*64
  const int fr = lane & 15;
  const int s4 = lane >> 4;

  const int id  = blockIdx.x;
  const int cpx = gridDim.x >> 3;
  const int sid = (id & 7) * cpx + (id >> 3);
  const int bm  = sid >> 3;                          // H/256 = 8 N-tiles
  const int bn  = sid & 7;
  const int m0 = bm * 256;
  const int n0 = bn * 256;

  const int c0 = tid, c1 = tid + 512;
  const int r0 = c0 >> 3, q0 = (c0 & 7) ^ ((r0 >> 1) & 7);
  const int r1 = c1 >> 3, q1 = (c1 & 7) ^ ((r1 >> 1) & 7);

  const uint16_t* gA00 = Act + (size_t)(m0 + r0) * K + q0 * 8;
  const uint16_t* gA01 = Act + (size_t)(m0 + r1) * K + q1 * 8;
  const uint16_t* gA10 = Act + (size_t)(m0 + 128 + r0) * K + q0 * 8;
  const uint16_t* gA11 = Act + (size_t)(m0 + 128 + r1) * K + q1 * 8;
  const uint16_t* gB00 = Wd  + (size_t)(n0 + r0) * K + q0 * 8;
  const uint16_t* gB01 = Wd  + (size_t)(n0 + r1) * K + q1 * 8;
  const uint16_t* gB10 = Wd  + (size_t)(n0 + 128 + r0) * K + q0 * 8;
  const uint16_t* gB11 = Wd  + (size_t)(n0 + 128 + r1) * K + q1 * 8;

  auto stageA = [&](int tt) {   // 4 loads
    uint16_t* d = sA + (tt & 1) * 16384;
    const size_t ko = (size_t)tt * 64;
    __builtin_amdgcn_global_load_lds((gv_t*)(gA00 + ko), (lv_t*)(d + c0 * 8), 16, 0, 0);
    __builtin_amdgcn_global_load_lds((gv_t*)(gA01 + ko), (lv_t*)(d + c1 * 8), 16, 0, 0);
    __builtin_amdgcn_global_load_lds((gv_t*)(gA10 + ko), (lv_t*)(d + 8192 + c0 * 8), 16, 0, 0);
    __builtin_amdgcn_global_load_lds((gv_t*)(gA11 + ko), (lv_t*)(d + 8192 + c1 * 8), 16, 0, 0);
  };
  auto stageB = [&](int tt) {   // 4 loads (both B halves)
    uint16_t* d = sB + (tt & 1) * 16384;
    const size_t ko = (size_t)tt * 64;
    __builtin_amdgcn_global_load_lds((gv_t*)(gB00 + ko), (lv_t*)(d + c0 * 8), 16, 0, 0);
    __builtin_amdgcn_global_load_lds((gv_t*)(gB01 + ko), (lv_t*)(d + c1 * 8), 16, 0, 0);
    __builtin_amdgcn_global_load_lds((gv_t*)(gB10 + ko), (lv_t*)(d + 8192 + c0 * 8), 16, 0, 0);
    __builtin_amdgcn_global_load_lds((gv_t*)(gB11 + ko), (lv_t*)(d + 8192 + c1 * 8), 16, 0, 0);
  };

  int offA[8], offB[4];
  #pragma unroll
  for (int mi = 0; mi < 8; mi++) {
    int r = wr * 128 + mi * 16 + fr;
    offA[mi] = r * 64 + ((s4 ^ ((r >> 1) & 7)) * 8);
  }
  #pragma unroll
  for (int ni = 0; ni < 4; ni++) {
    int r = wc * 64 + ni * 16 + fr;
    offB[ni] = r * 64 + ((s4 ^ ((r >> 1) & 7)) * 8);
  }

  f32x4 acc[8][4];
  #pragma unroll
  for (int i = 0; i < 8; i++)
    #pragma unroll
    for (int j = 0; j < 4; j++) acc[i][j] = (f32x4){0.f, 0.f, 0.f, 0.f};

  // prologue: tile0 complete + B of tile1 in flight
  stageA(0); stageB(0); stageB(1);
  asm volatile("s_waitcnt vmcnt(4)" ::: "memory");
  __builtin_amdgcn_s_barrier();
  asm volatile("" ::: "memory");

  #pragma unroll 2
  for (int t = 0; t < NT; ++t) {
    const uint16_t* a = sA + (t & 1) * 16384;
    const uint16_t* b = sB + (t & 1) * 16384;

    // ---- B fragment reads (must drain before B(t+2) same-buffer staging)
    bf16x8 bfr[4][2];
    #pragma unroll
    for (int ni = 0; ni < 4; ni++) {
      bfr[ni][0] = *(const bf16x8*)(b + offB[ni]);
      bfr[ni][1] = *(const bf16x8*)(b + (offB[ni] ^ 32));
    }
    if (t + 1 < NT) stageA(t + 1);                    // other buffer, WAR-safe
    asm volatile("s_waitcnt lgkmcnt(0)" ::: "memory");
    __builtin_amdgcn_s_barrier();                     // all waves' B reads done
    asm volatile("" ::: "memory");
    if (t + 2 < NT) stageB(t + 2);                    // overwrite sB[cur]

    // ---- A fragment reads; MFMAs overlap the reads ----
    bf16x8 al[4][2], ah[4][2];
    #pragma unroll
    for (int mi = 0; mi < 4; mi++) {
      al[mi][0] = *(const bf16x8*)(a + offA[mi]);
      al[mi][1] = *(const bf16x8*)(a + (offA[mi] ^ 32));
    }
    #pragma unroll
    for (int mi = 0; mi < 4; mi++) {
      ah[mi][0] = *(const bf16x8*)(a + offA[4 + mi]);
      ah[mi][1] = *(const bf16x8*)(a + (offA[4 + mi] ^ 32));
    }
    __builtin_amdgcn_s_setprio(1);
    #pragma unroll
    for (int mi = 0; mi < 4; mi++)
      #pragma unroll
      for (int ni = 0; ni < 4; ni++) {
        acc[mi][ni] = __builtin_amdgcn_mfma_f32_16x16x32_bf16(al[mi][0], bfr[ni][0], acc[mi][ni], 0, 0, 0);
        acc[mi][ni] = __builtin_amdgcn_mfma_f32_16x16x32_bf16(al[mi][1], bfr[ni][1], acc[mi][ni], 0, 0, 0);
      }
    #pragma unroll
    for (int mi = 0; mi < 4; mi++)
      #pragma unroll
      for (int ni = 0; ni < 4; ni++) {
        acc[4 + mi][ni] = __builtin_amdgcn_mfma_f32_16x16x32_bf16(ah[mi][0], bfr[ni][0], acc[4 + mi][ni], 0, 0, 0);
        acc[4 + mi][ni] = __builtin_amdgcn_mfma_f32_16x16x32_bf16(ah[mi][1], bfr[ni][1], acc[4 + mi][ni], 0, 0, 0);
      }
    __builtin_amdgcn_s_setprio(0);

    if (t + 2 < NT) { asm volatile("s_waitcnt vmcnt(4)" ::: "memory"); }
    else            { asm volatile("s_waitcnt vmcnt(0)" ::: "memory"); }
    __builtin_amdgcn_s_barrier();
    asm volatile("" ::: "memory");
  }

  const int rbase = s4 * 4;
  const int cbase = fr;
  #pragma unroll
  for (int mi = 0; mi < 8; mi++)
    #pragma unroll
    for (int ni = 0; ni < 4; ni++)
      #pragma unroll
      for (int i = 0; i < 4; i++) {
        int row = m0 + wr * 128 + mi * 16 + rbase + i;
        int col = n0 + wc * 64 + ni * 16 + cbase;
        size_t idx = (size_t)row * H_DIM + col;
        out[idx] = acc[mi][ni][i] + out[idx];
      }
}

// ---------------------------------------------------------------------------
// Kernel 4: aux loss scalar (fp32), bucketed accumulators
// ---------------------------------------------------------------------------
__global__ void aux_kernel(const float* __restrict__ accum,
                           float* __restrict__ out_aux)
{
  if (threadIdx.x == 0 && blockIdx.x == 0) {
    float s = 0.f;
    for (int e = 0; e < NEXP; e++) {
      float p = 0.f, c = 0.f;
      for (int b = 0; b < NBUCK; b++) {
        p += accum[e * NBUCK + b];
        c += accum[(NEXP + e) * NBUCK + b];
      }
      s += (p / (float)T_TOKENS) * (c / (float)T_TOKENS);
    }
    out_aux[0] = s * (float)NEXP * 0.01f;
  }
}

// ---------------------------------------------------------------------------
extern "C" void kernel_launch(void* const* d_in, const int* in_sizes, int n_in,
                              void* d_out, int out_size, void* d_ws, size_t ws_size,
                              hipStream_t stream) {
  const float* X  = (const float*)d_in[0];  // hidden_states [4,2048,2048] fp32
  const float* RW = (const float*)d_in[1];  // router_w [5,2048]
  const float* Wg = (const float*)d_in[2];  // gate_w [16384,2048]
  const float* Wu = (const float*)d_in[3];  // up_w [16384,2048]
  const float* Wd = (const float*)d_in[4];  // down_w [2048,16384]
  const float* LA = (const float*)d_in[5];  // lora_A [4,16,2048]
  const float* LB = (const float*)d_in[6];  // lora_B [4,2048,16]
  float* out = (float*)d_out;               // [4,2048,2048] fp32 + 1 aux

  char* ws = (char*)d_ws;
  uint16_t* Xb    = (uint16_t*)(ws);                         // 32 MiB bf16 [T,H]
  uint16_t* Wgb   = (uint16_t*)(ws + (size_t)32  * 1048576); // 64 MiB bf16 [I,H]
  uint16_t* Wub   = (uint16_t*)(ws + (size_t)96  * 1048576); // 64 MiB
  uint16_t* Wdb   = (uint16_t*)(ws + (size_t)160 * 1048576); // 64 MiB [H,I]
  uint16_t* act   = (uint16_t*)(ws + (size_t)224 * 1048576); // 256 MiB bf16 [T,I]
  float*    accum = (float*)   (ws + (size_t)480 * 1048576); // 10*NBUCK floats

  hipMemsetAsync(accum, 0, 2 * NEXP * NBUCK * sizeof(float), stream);

  const int nW = I_DIM * H_DIM;
  cvt_kernel<<<nW / 8 / 256, 256, 0, stream>>>(Wg, Wgb, nW / 8);
  cvt_kernel<<<nW / 8 / 256, 256, 0, stream>>>(Wu, Wub, nW / 8);
  cvt_kernel<<<nW / 8 / 256, 256, 0, stream>>>(Wd, Wdb, nW / 8);

  router_lora_kernel<<<T_TOKENS, 256, 0, stream>>>(X, RW, LA, LB, out, Xb, accum);
  gemm_gateup_kernel<<<(T_TOKENS / 256) * (I_DIM / 128), 512, 0, stream>>>(Xb, Wgb, Wub, act);
  gemm_down_kernel<<<(T_TOKENS / 256) * (H_DIM / 256), 512, 0, stream>>>(act, Wdb, out);
  aux_kernel<<<1, 64, 0, stream>>>(accum, out + (size_t)T_TOKENS * H_DIM);
}

// Round 3
// 2148.449 us; speedup vs baseline: 1.4196x; 1.1270x over previous
//
#include <hip/hip_runtime.h>
#include <stdint.h>
#include <math.h>

#define T_TOKENS 8192
#define H_DIM    2048
#define I_DIM    16384
#define NEXP     5
#define RANK     16
#define LORA_SCALE 2.0f
#define NBUCK    64

typedef __attribute__((ext_vector_type(8))) short bf16x8;   // 8 bf16 in 4 VGPRs
typedef __attribute__((ext_vector_type(4))) float f32x4;

typedef const __attribute__((address_space(1))) void gv_t;  // global
typedef __attribute__((address_space(3))) void lv_t;        // LDS

__device__ __forceinline__ uint16_t f2bf(float f) {
  union { uint32_t u; float f; } v; v.f = f;
  uint32_t u = v.u;
  return (uint16_t)((u + 0x7fffu + ((u >> 16) & 1u)) >> 16);
}
__device__ __forceinline__ uint32_t pack2(float lo, float hi) {
  return (uint32_t)f2bf(lo) | ((uint32_t)f2bf(hi) << 16);
}
// gelu_tanh(x) == x * sigmoid(2*0.7978845608*(x + 0.044715 x^3)); __expf -> v_exp_f32
__device__ __forceinline__ float gelu_fast(float x) {
  float x3 = x * x * x;
  float z = 1.5957691216057308f * (x + 0.044715f * x3);
  return x / (1.0f + __expf(-z));
}

// ---------------------------------------------------------------------------
// Kernel 0: fp32 -> bf16 conversion (8 elements / thread)
// ---------------------------------------------------------------------------
__global__ __launch_bounds__(256) void cvt_kernel(
    const float* __restrict__ src, uint16_t* __restrict__ dst, int n8)
{
  int i = blockIdx.x * 256 + threadIdx.x;
  if (i >= n8) return;
  float4 a = ((const float4*)src)[2 * i];
  float4 b = ((const float4*)src)[2 * i + 1];
  uint4 o;
  o.x = pack2(a.x, a.y);
  o.y = pack2(a.z, a.w);
  o.z = pack2(b.x, b.y);
  o.w = pack2(b.z, b.w);
  ((uint4*)dst)[i] = o;
}

// ---------------------------------------------------------------------------
// Kernel 1: router logits -> softmax stats + rank-16 LoRA (fp32 in).
// Also emits the bf16 copy of X. One block (256 threads) per token.
// ---------------------------------------------------------------------------
__global__ __launch_bounds__(256) void router_lora_kernel(
    const float* __restrict__ X,     // [T, H] fp32
    const float* __restrict__ RW,    // [5, H]
    const float* __restrict__ LA,    // [4, 16, H]
    const float* __restrict__ LB,    // [4, H, 16]
    float* __restrict__ lora_out,    // [T, H] fp32  (== d_out)
    uint16_t* __restrict__ Xb,       // [T, H] bf16
    float* __restrict__ accum)       // [10*NBUCK] fp32
{
  const int token = blockIdx.x;
  const int t = threadIdx.x;
  const int lane = t & 63, wid = t >> 6;

  __shared__ float red5[NEXP][4];
  __shared__ float logits_s[NEXP];
  __shared__ float tred[4][RANK];
  __shared__ float tvec[RANK];

  const float* x = X + (size_t)token * H_DIM;
  float4 xa = ((const float4*)x)[2 * t];
  float4 xb = ((const float4*)x)[2 * t + 1];
  float xv[8] = {xa.x, xa.y, xa.z, xa.w, xb.x, xb.y, xb.z, xb.w};

  // bf16 copy of X
  {
    uint4 o;
    o.x = pack2(xv[0], xv[1]);
    o.y = pack2(xv[2], xv[3]);
    o.z = pack2(xv[4], xv[5]);
    o.w = pack2(xv[6], xv[7]);
    ((uint4*)(Xb + (size_t)token * H_DIM))[t] = o;
  }

  // ---- logits ----
  float part[NEXP];
  #pragma unroll
  for (int e = 0; e < NEXP; e++) {
    const float* r = RW + e * H_DIM + t * 8;
    float4 ra = ((const float4*)r)[0];
    float4 rb = ((const float4*)r)[1];
    part[e] = xv[0]*ra.x + xv[1]*ra.y + xv[2]*ra.z + xv[3]*ra.w
            + xv[4]*rb.x + xv[5]*rb.y + xv[6]*rb.z + xv[7]*rb.w;
  }
  #pragma unroll
  for (int e = 0; e < NEXP; e++)
    #pragma unroll
    for (int off = 32; off > 0; off >>= 1)
      part[e] += __shfl_down(part[e], off, 64);
  if (lane == 0) {
    #pragma unroll
    for (int e = 0; e < NEXP; e++) red5[e][wid] = part[e];
  }
  __syncthreads();
  if (t == 0) {
    #pragma unroll
    for (int e = 0; e < NEXP; e++)
      logits_s[e] = red5[e][0] + red5[e][1] + red5[e][2] + red5[e][3];
  }
  __syncthreads();

  float lg[NEXP];
  #pragma unroll
  for (int e = 0; e < NEXP; e++) lg[e] = logits_s[e];
  int sel = 0; float best = lg[0];
  #pragma unroll
  for (int e = 1; e < NEXP; e++) if (lg[e] > best) { best = lg[e]; sel = e; }

  if (t == 0) {
    const int buck = blockIdx.x & (NBUCK - 1);
    float s = 0.f, p[NEXP];
    #pragma unroll
    for (int e = 0; e < NEXP; e++) { p[e] = __expf(lg[e] - best); s += p[e]; }
    float inv = 1.0f / s;
    #pragma unroll
    for (int e = 0; e < NEXP; e++) atomicAdd(&accum[e * NBUCK + buck], p[e] * inv);
    atomicAdd(&accum[(NEXP + sel) * NBUCK + buck], 1.0f);
  }

  // ---- LoRA correction (block-uniform branch) ----
  float outv[8] = {0.f,0.f,0.f,0.f,0.f,0.f,0.f,0.f};
  if (sel > 0) {
    const int e = sel - 1;
    const float* A = LA + (size_t)e * RANK * H_DIM;
    float tp[RANK];
    #pragma unroll
    for (int r = 0; r < RANK; r++) {
      const float* ar = A + r * H_DIM + t * 8;
      float4 a0 = ((const float4*)ar)[0];
      float4 a1 = ((const float4*)ar)[1];
      tp[r] = xv[0]*a0.x + xv[1]*a0.y + xv[2]*a0.z + xv[3]*a0.w
            + xv[4]*a1.x + xv[5]*a1.y + xv[6]*a1.z + xv[7]*a1.w;
    }
    #pragma unroll
    for (int r = 0; r < RANK; r++)
      #pragma unroll
      for (int off = 32; off > 0; off >>= 1)
        tp[r] += __shfl_down(tp[r], off, 64);
    if (lane == 0) {
      #pragma unroll
      for (int r = 0; r < RANK; r++) tred[wid][r] = tp[r];
    }
    __syncthreads();
    if (t < RANK) tvec[t] = tred[0][t] + tred[1][t] + tred[2][t] + tred[3][t];
    __syncthreads();

    const float* Bm = LB + (size_t)e * H_DIM * RANK;
    #pragma unroll
    for (int j = 0; j < 8; j++) {
      int h = t * 8 + j;
      const float* brow = Bm + h * RANK;
      float s = 0.f;
      #pragma unroll
      for (int r = 0; r < RANK; r += 4) {
        float4 b = ((const float4*)(brow + r))[0];
        s += tvec[r]*b.x + tvec[r+1]*b.y + tvec[r+2]*b.z + tvec[r+3]*b.w;
      }
      outv[j] = LORA_SCALE * s;
    }
  }
  float4* dst = (float4*)(lora_out + (size_t)token * H_DIM + t * 8);
  dst[0] = make_float4(outv[0], outv[1], outv[2], outv[3]);
  dst[1] = make_float4(outv[4], outv[5], outv[6], outv[7]);
}

// ===========================================================================
// GEMM kernels — 2 barriers per K-tile, reads overlapped with MFMA,
// fragment streaming to cap register pressure (round-2 spilled: 24 live
// frags = 96 VGPR + addr > 128 arch-VGPR budget -> scratch traffic, the
// +114 MB WRITE_SIZE).  Now at most ~16 frags live: the held operand (8)
// plus one streamed chunk (8); the compiler hoists the next chunk's
// ds_reads under the current MFMA cluster as registers free up.
//
// Hazard ledger (per thread, per K-tile t):
//  - issue other-buffer t+1 staging first (WAR-safe: that region's reads
//    completed in tile t-1 before its MFMA consumed them).
//  - read held-operand frags of buf[cur]; lgkmcnt(0); s_barrier ->
//    all waves' reads of the t+2-target region have drained.
//  - stage t+2 held-operand into buf[cur] (now safe).
//  - stream remaining frags + 64 MFMA.
//  - vmcnt(4): outstanding = [t+1:8][t+2:4] = 12 -> drains all of tile
//    t+1, leaves t+2's 4 loads in flight across the barrier.
// ===========================================================================

// ---------------------------------------------------------------------------
// Kernel 2: act = gelu(X @ Wg^T) * (X @ Wu^T), fused, tile 256x128.
// 8 waves 4Mx2N, per-wave 64x64 with g and u accumulators.
// ---------------------------------------------------------------------------
__global__ __launch_bounds__(512, 2) void gemm_gateup_kernel(
    const uint16_t* __restrict__ X,    // [T, H] bf16
    const uint16_t* __restrict__ Wg,   // [I, H] bf16
    const uint16_t* __restrict__ Wu,   // [I, H] bf16
    uint16_t* __restrict__ act)        // [T, I] bf16
{
  constexpr int K  = H_DIM;
  constexpr int NT = K / 64;                        // 32 K-tiles
  __shared__ __align__(16) uint16_t sA[2 * 16384];  // [buf][256][64]
  __shared__ __align__(16) uint16_t sG[2 * 8192];   // [buf][128][64]
  __shared__ __align__(16) uint16_t sU[2 * 8192];

  const int tid  = threadIdx.x;
  const int lane = tid & 63;
  const int wid  = tid >> 6;
  const int wr = wid >> 1;          // 0..3 -> M offset wr*64
  const int wc = wid & 1;           // 0..1 -> N offset wc*64
  const int fr = lane & 15;
  const int s4 = lane >> 4;

  // XCD-aware bijective swizzle (gridDim.x % 8 == 0)
  const int id  = blockIdx.x;
  const int cpx = gridDim.x >> 3;
  const int sid = (id & 7) * cpx + (id >> 3);
  const int bm  = sid >> 7;                          // I/128 = 128 N-tiles
  const int bn  = sid & 127;
  const int m0 = bm * 256;
  const int n0 = bn * 128;

  // staging: thread owns chunks (tid, tid+512) of each 1024-chunk half
  const int c0 = tid, c1 = tid + 512;
  const int r0 = c0 >> 3, q0 = (c0 & 7) ^ ((r0 >> 1) & 7);
  const int r1 = c1 >> 3, q1 = (c1 & 7) ^ ((r1 >> 1) & 7);

  const uint16_t* gA00 = X  + (size_t)(m0 + r0) * K + q0 * 8;
  const uint16_t* gA01 = X  + (size_t)(m0 + r1) * K + q1 * 8;
  const uint16_t* gA10 = X  + (size_t)(m0 + 128 + r0) * K + q0 * 8;
  const uint16_t* gA11 = X  + (size_t)(m0 + 128 + r1) * K + q1 * 8;
  const uint16_t* gG0  = Wg + (size_t)(n0 + r0) * K + q0 * 8;
  const uint16_t* gG1  = Wg + (size_t)(n0 + r1) * K + q1 * 8;
  const uint16_t* gU0  = Wu + (size_t)(n0 + r0) * K + q0 * 8;
  const uint16_t* gU1  = Wu + (size_t)(n0 + r1) * K + q1 * 8;

  auto stageA = [&](int tt) {   // 4 loads: both A halves
    uint16_t* d = sA + (tt & 1) * 16384;
    const size_t ko = (size_t)tt * 64;
    __builtin_amdgcn_global_load_lds((gv_t*)(gA00 + ko), (lv_t*)(d + c0 * 8), 16, 0, 0);
    __builtin_amdgcn_global_load_lds((gv_t*)(gA01 + ko), (lv_t*)(d + c1 * 8), 16, 0, 0);
    __builtin_amdgcn_global_load_lds((gv_t*)(gA10 + ko), (lv_t*)(d + 8192 + c0 * 8), 16, 0, 0);
    __builtin_amdgcn_global_load_lds((gv_t*)(gA11 + ko), (lv_t*)(d + 8192 + c1 * 8), 16, 0, 0);
  };
  auto stageG = [&](int tt) {   // 2 loads
    uint16_t* d = sG + (tt & 1) * 8192;
    const size_t ko = (size_t)tt * 64;
    __builtin_amdgcn_global_load_lds((gv_t*)(gG0 + ko), (lv_t*)(d + c0 * 8), 16, 0, 0);
    __builtin_amdgcn_global_load_lds((gv_t*)(gG1 + ko), (lv_t*)(d + c1 * 8), 16, 0, 0);
  };
  auto stageU = [&](int tt) {   // 2 loads
    uint16_t* d = sU + (tt & 1) * 8192;
    const size_t ko = (size_t)tt * 64;
    __builtin_amdgcn_global_load_lds((gv_t*)(gU0 + ko), (lv_t*)(d + c0 * 8), 16, 0, 0);
    __builtin_amdgcn_global_load_lds((gv_t*)(gU1 + ko), (lv_t*)(d + c1 * 8), 16, 0, 0);
  };

  // fragment LDS element offsets for kk=0; kk=1 is ^32 (chunk bit2 flip)
  int offA[4], offB[4];
  #pragma unroll
  for (int mi = 0; mi < 4; mi++) {
    int r = wr * 64 + mi * 16 + fr;
    offA[mi] = r * 64 + ((s4 ^ ((r >> 1) & 7)) * 8);
  }
  #pragma unroll
  for (int ni = 0; ni < 4; ni++) {
    int r = wc * 64 + ni * 16 + fr;
    offB[ni] = r * 64 + ((s4 ^ ((r >> 1) & 7)) * 8);
  }

  f32x4 accg[4][4], accu[4][4];
  #pragma unroll
  for (int i = 0; i < 4; i++)
    #pragma unroll
    for (int j = 0; j < 4; j++) {
      accg[i][j] = (f32x4){0.f, 0.f, 0.f, 0.f};
      accu[i][j] = (f32x4){0.f, 0.f, 0.f, 0.f};
    }

  // prologue: tile0 complete (8 loads) + A of tile1 (4 loads)
  stageA(0); stageG(0); stageU(0); stageA(1);
  asm volatile("s_waitcnt vmcnt(4)" ::: "memory");
  __builtin_amdgcn_s_barrier();
  asm volatile("" ::: "memory");

  #pragma unroll 2
  for (int t = 0; t < NT; ++t) {
    const uint16_t* a  = sA + (t & 1) * 16384;
    const uint16_t* gq = sG + (t & 1) * 8192;
    const uint16_t* uq = sU + (t & 1) * 8192;

    // stage next tile's G,U into the other buffer (WAR-safe post tile t-1)
    if (t + 1 < NT) { stageG(t + 1); stageU(t + 1); }

    // ---- A fragment reads (must drain before A(t+2) same-buffer staging)
    bf16x8 af[4][2];
    #pragma unroll
    for (int mi = 0; mi < 4; mi++) {
      af[mi][0] = *(const bf16x8*)(a + offA[mi]);
      af[mi][1] = *(const bf16x8*)(a + (offA[mi] ^ 32));
    }
    asm volatile("s_waitcnt lgkmcnt(0)" ::: "memory");
    __builtin_amdgcn_s_barrier();                     // all waves' A reads done
    asm volatile("" ::: "memory");
    if (t + 2 < NT) stageA(t + 2);                    // overwrite sA[cur]

    // ---- stream G frags, then accg MFMAs ----
    {
      bf16x8 gf[4][2];
      #pragma unroll
      for (int ni = 0; ni < 4; ni++) {
        gf[ni][0] = *(const bf16x8*)(gq + offB[ni]);
        gf[ni][1] = *(const bf16x8*)(gq + (offB[ni] ^ 32));
      }
      __builtin_amdgcn_s_setprio(1);
      #pragma unroll
      for (int mi = 0; mi < 4; mi++)
        #pragma unroll
        for (int ni = 0; ni < 4; ni++) {
          accg[mi][ni] = __builtin_amdgcn_mfma_f32_16x16x32_bf16(af[mi][0], gf[ni][0], accg[mi][ni], 0, 0, 0);
          accg[mi][ni] = __builtin_amdgcn_mfma_f32_16x16x32_bf16(af[mi][1], gf[ni][1], accg[mi][ni], 0, 0, 0);
        }
      __builtin_amdgcn_s_setprio(0);
    }
    // ---- stream U frags, then accu MFMAs ----
    {
      bf16x8 uf[4][2];
      #pragma unroll
      for (int ni = 0; ni < 4; ni++) {
        uf[ni][0] = *(const bf16x8*)(uq + offB[ni]);
        uf[ni][1] = *(const bf16x8*)(uq + (offB[ni] ^ 32));
      }
      __builtin_amdgcn_s_setprio(1);
      #pragma unroll
      for (int mi = 0; mi < 4; mi++)
        #pragma unroll
        for (int ni = 0; ni < 4; ni++) {
          accu[mi][ni] = __builtin_amdgcn_mfma_f32_16x16x32_bf16(af[mi][0], uf[ni][0], accu[mi][ni], 0, 0, 0);
          accu[mi][ni] = __builtin_amdgcn_mfma_f32_16x16x32_bf16(af[mi][1], uf[ni][1], accu[mi][ni], 0, 0, 0);
        }
      __builtin_amdgcn_s_setprio(0);
    }

    if (t + 2 < NT) { asm volatile("s_waitcnt vmcnt(4)" ::: "memory"); }
    else            { asm volatile("s_waitcnt vmcnt(0)" ::: "memory"); }
    __builtin_amdgcn_s_barrier();
    asm volatile("" ::: "memory");
  }

  // epilogue: C/D layout col=lane&15, row=(lane>>4)*4+reg  [m89-verified]
  const int rbase = s4 * 4;
  const int cbase = fr;
  #pragma unroll
  for (int mi = 0; mi < 4; mi++)
    #pragma unroll
    for (int ni = 0; ni < 4; ni++)
      #pragma unroll
      for (int i = 0; i < 4; i++) {
        int row = m0 + wr * 64 + mi * 16 + rbase + i;
        int col = n0 + wc * 64 + ni * 16 + cbase;
        float g = accg[mi][ni][i];
        float u = accu[mi][ni][i];
        act[(size_t)row * I_DIM + col] = f2bf(gelu_fast(g) * u);
      }
}

// ---------------------------------------------------------------------------
// Kernel 3: out = act @ Wd^T + lora  (Wd stored [H, I] == B^T form)
// 256x256 tile, 8 waves 2Mx4N, per-wave 128x64.  B (8 frag reads) is the
// held operand; A streams in two 8-frag chunks around the MFMA clusters.
// ---------------------------------------------------------------------------
__global__ __launch_bounds__(512, 2) void gemm_down_kernel(
    const uint16_t* __restrict__ Act,  // [T, I] bf16
    const uint16_t* __restrict__ Wd,   // [H, I] bf16
    float* __restrict__ out)           // [T, H] fp32 (holds lora on entry)
{
  constexpr int K  = I_DIM;
  constexpr int NT = K / 64;                         // 256 K-tiles
  __shared__ __align__(16) uint16_t sA[2 * 16384];   // [buf][256][64]
  __shared__ __align__(16) uint16_t sB[2 * 16384];

  const int tid  = threadIdx.x;
  const int lane = tid & 63;
  const int wid  = tid >> 6;
  const int wr = wid >> 2;          // 0..1 -> M offset wr*128
  const int wc = wid & 3;           // 0..3 -> N offset wc*64
  const int fr = lane & 15;
  const int s4 = lane >> 4;

  const int id  = blockIdx.x;
  const int cpx = gridDim.x >> 3;
  const int sid = (id & 7) * cpx + (id >> 3);
  const int bm  = sid >> 3;                          // H/256 = 8 N-tiles
  const int bn  = sid & 7;
  const int m0 = bm * 256;
  const int n0 = bn * 256;

  const int c0 = tid, c1 = tid + 512;
  const int r0 = c0 >> 3, q0 = (c0 & 7) ^ ((r0 >> 1) & 7);
  const int r1 = c1 >> 3, q1 = (c1 & 7) ^ ((r1 >> 1) & 7);

  const uint16_t* gA00 = Act + (size_t)(m0 + r0) * K + q0 * 8;
  const uint16_t* gA01 = Act + (size_t)(m0 + r1) * K + q1 * 8;
  const uint16_t* gA10 = Act + (size_t)(m0 + 128 + r0) * K + q0 * 8;
  const uint16_t* gA11 = Act + (size_t)(m0 + 128 + r1) * K + q1 * 8;
  const uint16_t* gB00 = Wd  + (size_t)(n0 + r0) * K + q0 * 8;
  const uint16_t* gB01 = Wd  + (size_t)(n0 + r1) * K + q1 * 8;
  const uint16_t* gB10 = Wd  + (size_t)(n0 + 128 + r0) * K + q0 * 8;
  const uint16_t* gB11 = Wd  + (size_t)(n0 + 128 + r1) * K + q1 * 8;

  auto stageA = [&](int tt) {   // 4 loads
    uint16_t* d = sA + (tt & 1) * 16384;
    const size_t ko = (size_t)tt * 64;
    __builtin_amdgcn_global_load_lds((gv_t*)(gA00 + ko), (lv_t*)(d + c0 * 8), 16, 0, 0);
    __builtin_amdgcn_global_load_lds((gv_t*)(gA01 + ko), (lv_t*)(d + c1 * 8), 16, 0, 0);
    __builtin_amdgcn_global_load_lds((gv_t*)(gA10 + ko), (lv_t*)(d + 8192 + c0 * 8), 16, 0, 0);
    __builtin_amdgcn_global_load_lds((gv_t*)(gA11 + ko), (lv_t*)(d + 8192 + c1 * 8), 16, 0, 0);
  };
  auto stageB = [&](int tt) {   // 4 loads (both B halves)
    uint16_t* d = sB + (tt & 1) * 16384;
    const size_t ko = (size_t)tt * 64;
    __builtin_amdgcn_global_load_lds((gv_t*)(gB00 + ko), (lv_t*)(d + c0 * 8), 16, 0, 0);
    __builtin_amdgcn_global_load_lds((gv_t*)(gB01 + ko), (lv_t*)(d + c1 * 8), 16, 0, 0);
    __builtin_amdgcn_global_load_lds((gv_t*)(gB10 + ko), (lv_t*)(d + 8192 + c0 * 8), 16, 0, 0);
    __builtin_amdgcn_global_load_lds((gv_t*)(gB11 + ko), (lv_t*)(d + 8192 + c1 * 8), 16, 0, 0);
  };

  int offA[8], offB[4];
  #pragma unroll
  for (int mi = 0; mi < 8; mi++) {
    int r = wr * 128 + mi * 16 + fr;
    offA[mi] = r * 64 + ((s4 ^ ((r >> 1) & 7)) * 8);
  }
  #pragma unroll
  for (int ni = 0; ni < 4; ni++) {
    int r = wc * 64 + ni * 16 + fr;
    offB[ni] = r * 64 + ((s4 ^ ((r >> 1) & 7)) * 8);
  }

  f32x4 acc[8][4];
  #pragma unroll
  for (int i = 0; i < 8; i++)
    #pragma unroll
    for (int j = 0; j < 4; j++) acc[i][j] = (f32x4){0.f, 0.f, 0.f, 0.f};

  // prologue: tile0 complete + B of tile1 in flight
  stageA(0); stageB(0); stageB(1);
  asm volatile("s_waitcnt vmcnt(4)" ::: "memory");
  __builtin_amdgcn_s_barrier();
  asm volatile("" ::: "memory");

  #pragma unroll 2
  for (int t = 0; t < NT; ++t) {
    const uint16_t* a = sA + (t & 1) * 16384;
    const uint16_t* b = sB + (t & 1) * 16384;

    if (t + 1 < NT) stageA(t + 1);                    // other buffer, WAR-safe

    // ---- B fragment reads (must drain before B(t+2) same-buffer staging)
    bf16x8 bfr[4][2];
    #pragma unroll
    for (int ni = 0; ni < 4; ni++) {
      bfr[ni][0] = *(const bf16x8*)(b + offB[ni]);
      bfr[ni][1] = *(const bf16x8*)(b + (offB[ni] ^ 32));
    }
    asm volatile("s_waitcnt lgkmcnt(0)" ::: "memory");
    __builtin_amdgcn_s_barrier();                     // all waves' B reads done
    asm volatile("" ::: "memory");
    if (t + 2 < NT) stageB(t + 2);                    // overwrite sB[cur]

    // ---- stream A-lo frags, MFMA rows 0..3 ----
    {
      bf16x8 al[4][2];
      #pragma unroll
      for (int mi = 0; mi < 4; mi++) {
        al[mi][0] = *(const bf16x8*)(a + offA[mi]);
        al[mi][1] = *(const bf16x8*)(a + (offA[mi] ^ 32));
      }
      __builtin_amdgcn_s_setprio(1);
      #pragma unroll
      for (int mi = 0; mi < 4; mi++)
        #pragma unroll
        for (int ni = 0; ni < 4; ni++) {
          acc[mi][ni] = __builtin_amdgcn_mfma_f32_16x16x32_bf16(al[mi][0], bfr[ni][0], acc[mi][ni], 0, 0, 0);
          acc[mi][ni] = __builtin_amdgcn_mfma_f32_16x16x32_bf16(al[mi][1], bfr[ni][1], acc[mi][ni], 0, 0, 0);
        }
      __builtin_amdgcn_s_setprio(0);
    }
    // ---- stream A-hi frags, MFMA rows 4..7 ----
    {
      bf16x8 ah[4][2];
      #pragma unroll
      for (int mi = 0; mi < 4; mi++) {
        ah[mi][0] = *(const bf16x8*)(a + offA[4 + mi]);
        ah[mi][1] = *(const bf16x8*)(a + (offA[4 + mi] ^ 32));
      }
      __builtin_amdgcn_s_setprio(1);
      #pragma unroll
      for (int mi = 0; mi < 4; mi++)
        #pragma unroll
        for (int ni = 0; ni < 4; ni++) {
          acc[4 + mi][ni] = __builtin_amdgcn_mfma_f32_16x16x32_bf16(ah[mi][0], bfr[ni][0], acc[4 + mi][ni], 0, 0, 0);
          acc[4 + mi][ni] = __builtin_amdgcn_mfma_f32_16x16x32_bf16(ah[mi][1], bfr[ni][1], acc[4 + mi][ni], 0, 0, 0);
        }
      __builtin_amdgcn_s_setprio(0);
    }

    if (t + 2 < NT) { asm volatile("s_waitcnt vmcnt(4)" ::: "memory"); }
    else            { asm volatile("s_waitcnt vmcnt(0)" ::: "memory"); }
    __builtin_amdgcn_s_barrier();
    asm volatile("" ::: "memory");
  }

  const int rbase = s4 * 4;
  const int cbase = fr;
  #pragma unroll
  for (int mi = 0; mi < 8; mi++)
    #pragma unroll
    for (int ni = 0; ni < 4; ni++)
      #pragma unroll
      for (int i = 0; i < 4; i++) {
        int row = m0 + wr * 128 + mi * 16 + rbase + i;
        int col = n0 + wc * 64 + ni * 16 + cbase;
        size_t idx = (size_t)row * H_DIM + col;
        out[idx] = acc[mi][ni][i] + out[idx];
      }
}

// ---------------------------------------------------------------------------
// Kernel 4: aux loss scalar (fp32), bucketed accumulators
// ---------------------------------------------------------------------------
__global__ void aux_kernel(const float* __restrict__ accum,
                           float* __restrict__ out_aux)
{
  if (threadIdx.x == 0 && blockIdx.x == 0) {
    float s = 0.f;
    for (int e = 0; e < NEXP; e++) {
      float p = 0.f, c = 0.f;
      for (int b = 0; b < NBUCK; b++) {
        p += accum[e * NBUCK + b];
        c += accum[(NEXP + e) * NBUCK + b];
      }
      s += (p / (float)T_TOKENS) * (c / (float)T_TOKENS);
    }
    out_aux[0] = s * (float)NEXP * 0.01f;
  }
}

// ---------------------------------------------------------------------------
extern "C" void kernel_launch(void* const* d_in, const int* in_sizes, int n_in,
                              void* d_out, int out_size, void* d_ws, size_t ws_size,
                              hipStream_t stream) {
  const float* X  = (const float*)d_in[0];  // hidden_states [4,2048,2048] fp32
  const float* RW = (const float*)d_in[1];  // router_w [5,2048]
  const float* Wg = (const float*)d_in[2];  // gate_w [16384,2048]
  const float* Wu = (const float*)d_in[3];  // up_w [16384,2048]
  const float* Wd = (const float*)d_in[4];  // down_w [2048,16384]
  const float* LA = (const float*)d_in[5];  // lora_A [4,16,2048]
  const float* LB = (const float*)d_in[6];  // lora_B [4,2048,16]
  float* out = (float*)d_out;               // [4,2048,2048] fp32 + 1 aux

  char* ws = (char*)d_ws;
  uint16_t* Xb    = (uint16_t*)(ws);                         // 32 MiB bf16 [T,H]
  uint16_t* Wgb   = (uint16_t*)(ws + (size_t)32  * 1048576); // 64 MiB bf16 [I,H]
  uint16_t* Wub   = (uint16_t*)(ws + (size_t)96  * 1048576); // 64 MiB
  uint16_t* Wdb   = (uint16_t*)(ws + (size_t)160 * 1048576); // 64 MiB [H,I]
  uint16_t* act   = (uint16_t*)(ws + (size_t)224 * 1048576); // 256 MiB bf16 [T,I]
  float*    accum = (float*)   (ws + (size_t)480 * 1048576); // 10*NBUCK floats

  hipMemsetAsync(accum, 0, 2 * NEXP * NBUCK * sizeof(float), stream);

  const int nW = I_DIM * H_DIM;
  cvt_kernel<<<nW / 8 / 256, 256, 0, stream>>>(Wg, Wgb, nW / 8);
  cvt_kernel<<<nW / 8 / 256, 256, 0, stream>>>(Wu, Wub, nW / 8);
  cvt_kernel<<<nW / 8 / 256, 256, 0, stream>>>(Wd, Wdb, nW / 8);

  router_lora_kernel<<<T_TOKENS, 256, 0, stream>>>(X, RW, LA, LB, out, Xb, accum);
  gemm_gateup_kernel<<<(T_TOKENS / 256) * (I_DIM / 128), 512, 0, stream>>>(Xb, Wgb, Wub, act);
  gemm_down_kernel<<<(T_TOKENS / 256) * (H_DIM / 256), 512, 0, stream>>>(act, Wdb, out);
  aux_kernel<<<1, 64, 0, stream>>>(accum, out + (size_t)T_TOKENS * H_DIM);
}